// Round 8
// baseline (49.743 us; speedup 1.0000x reference)
//
#include <hip/hip_runtime.h>
#include <hip/hip_bf16.h>

// BERT_CRF, single-kernel: R2's proven quarter-partitioned MFMA K1 (best
// wall: 40.07 us as K1+K2) with the comb phase fused via end-of-kernel
// election. B=64, T=512, H=768, L=9.
//
// Producers (256 blocks x 512 thr, one (batch, quarter) each):
//   R2-proven body VERBATIM: W staged as bf16 MFMA B-frags in LDS, 8 waves
//   x 16 rows x 24 MFMA k-steps, exp(em)->LDS, numerator partials, 8 chunk
//   products (CS=16), pair-combine 8->4->2->1 -> quarter matrix to global.
//   Then: __syncthreads (drains stores), tid0 does RELEASE-scope
//   atomicAdd(cnt) -- wbl2 only, no L2 invalidate (R1's catastrophe was
//   producers' full __threadfence: 512 buffer_invs evicting streamed wv).
// Finisher (the block seeing old==255): single ACQUIRE (one L2 inv, after
//   all streaming done), then folds all 64 batches with 32 x 16-lane
//   groups (2 passes), math byte-identical to the proven comb_kernel
//   serial fold; writes out[0]. cnt zeroed by a 4-byte hipMemsetAsync.

#define Bn 64
#define Tn 512
#define Hn 768
#define Ln 9
#define EMS 12     // padded LDS emission row stride (floats)
#define CS 16      // time steps per chunk
#define NCHQ 8     // chunks per quarter
#define QT 128     // timesteps per block
#define KSTEPS 24  // 768 / 32
#define NBLKS 256

typedef short bf16x8 __attribute__((ext_vector_type(8)));   // 8 bf16 (4 VGPRs)
typedef float f32x4  __attribute__((ext_vector_type(4)));   // 4 fp32 acc

__device__ __forceinline__ short f2bf(float f) {
    return (short)__builtin_bit_cast(unsigned short, __float2bfloat16(f));
}

// ---------------- fused kernel ----------------
__global__ __launch_bounds__(512) void emis_q_kernel(
    const float* __restrict__ wv, const float* __restrict__ Wm,
    const float* __restrict__ bias, const int* __restrict__ mask,
    const int* __restrict__ label, const float* __restrict__ trans,
    const float* __restrict__ startT, const float* __restrict__ endT,
    float* __restrict__ Mq, float* __restrict__ lgq,
    float* __restrict__ numq, int* __restrict__ msq,
    float* __restrict__ em0, int* __restrict__ cnt,
    float* __restrict__ out)
{
    __shared__ bf16x8 wlds[KSTEPS * 64];     // 24576 B, W B-fragments
    __shared__ float  ldsE[QT][EMS];         // exp(emissions), 6144 B
    __shared__ int    ldsM[QT];              // mask slice
    __shared__ float  eTs[81];               // exp(transitions)
    __shared__ float  sM[NCHQ][Ln][Ln];      // chunk product matrices
    __shared__ float  sLg[NCHQ][Ln];         // chunk row log-scales
    __shared__ float  sp[8];
    __shared__ int    si[8];
    __shared__ float  nllArr[Bn];            // finisher per-batch NLLs
    __shared__ int    sOld;

    const int tid   = threadIdx.x;
    const int lane  = tid & 63;
    const int wid   = tid >> 6;
    const int bid   = blockIdx.x;
    const int b     = bid >> 2;
    const int q     = bid & 3;
    const int tbase = q * QT;

    if (tid < 81) eTs[tid] = __expf(trans[tid]);

    // Stage W (L=9 x H=768 fp32) as bf16 B-fragments in MFMA lane order:
    // entry (kk, lane): lane holds B[k = kk*32 + (lane>>4)*8 + j][n = lane&15],
    // B[k][n] = W[n][k]; n >= 9 -> zeros.
    for (int idx = tid; idx < KSTEPS * 64; idx += 512) {
        const int kk = idx >> 6, ln = idx & 63;
        const int n = ln & 15, kb2 = ln >> 4;
        bf16x8 v;
        if (n < Ln) {
            const float* src = Wm + n * Hn + kk * 32 + kb2 * 8;
#pragma unroll
            for (int j = 0; j < 8; ++j) v[j] = f2bf(src[j]);
        } else {
#pragma unroll
            for (int j = 0; j < 8; ++j) v[j] = 0;
        }
        wlds[idx] = v;
    }
    __syncthreads();

    // ---- emission phase: wave wid computes rows [bid*128 + wid*16, +16) ----
    {
        const int m  = lane & 15;            // A row within tile
        const int kb = lane >> 4;            // k-subblock (8 elems)
        const float* abase = wv + (size_t)(bid * QT + wid * 16 + m) * Hn + kb * 8;

        f32x4 acc = {0.f, 0.f, 0.f, 0.f};
#pragma unroll 4
        for (int kk = 0; kk < KSTEPS; ++kk) {
            float4 x0 = *reinterpret_cast<const float4*>(abase + kk * 32);
            float4 x1 = *reinterpret_cast<const float4*>(abase + kk * 32 + 4);
            bf16x8 a;
            a[0] = f2bf(x0.x); a[1] = f2bf(x0.y); a[2] = f2bf(x0.z); a[3] = f2bf(x0.w);
            a[4] = f2bf(x1.x); a[5] = f2bf(x1.y); a[6] = f2bf(x1.z); a[7] = f2bf(x1.w);
            bf16x8 bfr = wlds[kk * 64 + lane];
            acc = __builtin_amdgcn_mfma_f32_16x16x32_bf16(a, bfr, acc, 0, 0, 0);
        }
        // C/D layout: col = lane&15, row = (lane>>4)*4 + r. Write exp to LDS.
        const int l = lane & 15;
        if (l < Ln) {
            const float bl = bias[l];
#pragma unroll
            for (int r = 0; r < 4; ++r) {
                const int lrow = wid * 16 + (lane >> 4) * 4 + r;
                ldsE[lrow][l] = __expf(acc[r] + bl);
            }
        }
    }
    __syncthreads();

    // ---- numerator partials + mask staging (threads 0..127, one t each) ----
    float part = 0.f; int ms = 0;
    if (tid < QT) {
        const int gt  = tbase + tid;
        const int tag = label[b * Tn + gt];
        const int mk  = mask[b * Tn + gt];
        ldsM[tid] = mk; ms = mk;
        if (gt == 0) {
            part = startT[tag] + __logf(ldsE[0][tag]);
        } else if (mk) {
            const int prev = label[b * Tn + gt - 1];
            part = trans[prev * Ln + tag] + __logf(ldsE[tid][tag]);
        }
    }
#pragma unroll
    for (int off = 32; off > 0; off >>= 1) {
        part += __shfl_xor(part, off);
        ms   += __shfl_xor(ms, off);
    }
    if (lane == 0) { sp[wid] = part; si[wid] = ms; }
    __syncthreads();

    // ---- chunk products (threads 0..71), all operands from LDS ----
    if (tid < NCHQ * Ln) {
        float Tr[81];
#pragma unroll
        for (int i = 0; i < 81; ++i) Tr[i] = eTs[i];
        const int r = tid % Ln;
        const int c = tid / Ln;

        float v[9];
#pragma unroll
        for (int k = 0; k < 9; ++k) v[k] = (k == r) ? 1.f : 0.f;
        float lg = 0.f;

        int t0 = tbase + c * CS; if (t0 == 0) t0 = 1;   // only (q==0,c==0)
        const int t1 = tbase + (c + 1) * CS;

        int lt = t0 - tbase;
        float4 e0v = *reinterpret_cast<const float4*>(&ldsE[lt][0]);
        float4 e1v = *reinterpret_cast<const float4*>(&ldsE[lt][4]);
        float  e8  = ldsE[lt][8];
        int    mk  = ldsM[lt];

        for (int t = t0; t < t1; ++t) {
            float4 p0 = make_float4(0.f, 0.f, 0.f, 0.f), p1 = p0;
            float  p8 = 0.f; int pm = 0;
            if (t + 1 < t1) {
                const int nlt = t + 1 - tbase;
                p0 = *reinterpret_cast<const float4*>(&ldsE[nlt][0]);
                p1 = *reinterpret_cast<const float4*>(&ldsE[nlt][4]);
                p8 = ldsE[nlt][8];
                pm = ldsM[nlt];
            }
            if (mk) {
                float e[9] = {e0v.x, e0v.y, e0v.z, e0v.w, e1v.x, e1v.y, e1v.z, e1v.w, e8};
                float nv[9];
#pragma unroll
                for (int jj = 0; jj < 9; ++jj) {
                    float acc = v[0] * Tr[jj];
#pragma unroll
                    for (int k = 1; k < 9; ++k) acc += v[k] * Tr[k * 9 + jj];
                    nv[jj] = acc * e[jj];
                }
                float mx = nv[0];
#pragma unroll
                for (int jj = 1; jj < 9; ++jj) mx = fmaxf(mx, nv[jj]);
                float inv = 1.f / mx;
#pragma unroll
                for (int jj = 0; jj < 9; ++jj) v[jj] = nv[jj] * inv;
                lg += __logf(mx);
            }
            e0v = p0; e1v = p1; e8 = p8; mk = pm;
        }
#pragma unroll
        for (int jj = 0; jj < 9; ++jj) sM[c][r][jj] = v[jj];
        sLg[c][r] = lg;
    }
    // parallel small outputs (independent of chunk phase)
    if (q == 0 && tid >= 72 && tid < 81) em0[b * Ln + (tid - 72)] = ldsE[0][tid - 72];
    if (tid == 100) {
        float s = 0.f; int m2 = 0;
#pragma unroll
        for (int i = 0; i < 8; ++i) { s += sp[i]; m2 += si[i]; }
        numq[bid] = s; msq[bid] = m2;
    }
    __syncthreads();

    // ---- pair-combine 8 -> 4 -> 2 (in place, barrier-separated) ----
    for (int n = 4; n >= 2; n >>= 1) {
        float vout[9]; float lgout = 0.f;
        const bool act = tid < n * Ln;
        int p = 0, r = 0;
        if (act) {
            p = tid / Ln; r = tid % Ln;
            float mB = sLg[2 * p + 1][0];
#pragma unroll
            for (int k = 1; k < 9; ++k) mB = fmaxf(mB, sLg[2 * p + 1][k]);
            float tA[9];
#pragma unroll
            for (int k = 0; k < 9; ++k) tA[k] = sM[2 * p][r][k] * __expf(sLg[2 * p + 1][k] - mB);
#pragma unroll
            for (int jj = 0; jj < 9; ++jj) {
                float acc = tA[0] * sM[2 * p + 1][0][jj];
#pragma unroll
                for (int k = 1; k < 9; ++k) acc += tA[k] * sM[2 * p + 1][k][jj];
                vout[jj] = acc;
            }
            float mx = vout[0];
#pragma unroll
            for (int jj = 1; jj < 9; ++jj) mx = fmaxf(mx, vout[jj]);
            float inv = 1.f / mx;
#pragma unroll
            for (int jj = 0; jj < 9; ++jj) vout[jj] *= inv;
            lgout = sLg[2 * p][r] + mB + __logf(mx);
        }
        __syncthreads();
        if (act) {
#pragma unroll
            for (int jj = 0; jj < 9; ++jj) sM[p][r][jj] = vout[jj];
            sLg[p][r] = lgout;
        }
        __syncthreads();
    }

    // ---- final pair -> global quarter matrix ----
    if (tid < Ln) {
        const int r = tid;
        float mB = sLg[1][0];
#pragma unroll
        for (int k = 1; k < 9; ++k) mB = fmaxf(mB, sLg[1][k]);
        float tA[9];
#pragma unroll
        for (int k = 0; k < 9; ++k) tA[k] = sM[0][r][k] * __expf(sLg[1][k] - mB);
        float v[9];
#pragma unroll
        for (int jj = 0; jj < 9; ++jj) {
            float acc = tA[0] * sM[1][0][jj];
#pragma unroll
            for (int k = 1; k < 9; ++k) acc += tA[k] * sM[1][k][jj];
            v[jj] = acc;
        }
        float mx = v[0];
#pragma unroll
        for (int jj = 1; jj < 9; ++jj) mx = fmaxf(mx, v[jj]);
        float inv = 1.f / mx;
#pragma unroll
        for (int jj = 0; jj < 9; ++jj) Mq[bid * 81 + r * 9 + jj] = v[jj] * inv;
        lgq[bid * Ln + r] = sLg[0][r] + mB + __logf(mx);
    }

    // ---------------- election: release-only publish ----------------
    __syncthreads();     // compiler drains vmcnt before s_barrier: stores in L2
    if (tid == 0) {
        // RELEASE at agent scope: wbl2 (writeback dirty lines; wv is clean
        // -> cheap). NO invalidate here (R1's mistake).
        sOld = __hip_atomic_fetch_add(cnt, 1, __ATOMIC_RELEASE,
                                      __HIP_MEMORY_SCOPE_AGENT);
    }
    __syncthreads();
    if (sOld != NBLKS - 1) return;

    // ---------------- finisher: fold all 64 batches ----------------
    if (tid == 0) {
        // single ACQUIRE: one L2 invalidate, after all streaming is done
        (void)__hip_atomic_load(cnt, __ATOMIC_ACQUIRE, __HIP_MEMORY_SCOPE_AGENT);
    }
    __syncthreads();

    {
        const int lj = tid & 15;             // lane within 16-lane group
        const int g  = tid >> 4;             // group 0..31
        const float NEG = -1e30f;
#pragma unroll
        for (int pass = 0; pass < 2; ++pass) {
            const int bb = g + pass * 32;
            // proven serial fold of 4 quarter matrices (comb_kernel math,
            // operands direct from global -- tiny, L2-hot)
            float la = (lj < Ln) ? (startT[lj] + __logf(em0[bb * Ln + lj])) : NEG;
            for (int c = 0; c < 4; ++c) {
                const float* Mc = Mq + (bb * 4 + c) * 81;
                float mc[9];
#pragma unroll
                for (int rr = 0; rr < 9; ++rr) mc[rr] = (lj < Ln) ? Mc[rr * 9 + lj] : 0.f;
                float x = (lj < Ln) ? (la + lgq[(bb * 4 + c) * Ln + lj]) : NEG;
                float mm = x;
#pragma unroll
                for (int off = 1; off < 16; off <<= 1) mm = fmaxf(mm, __shfl_xor(mm, off, 16));
                float w = __expf(x - mm);                 // lj>=9 -> 0
                float sacc = 0.f;
#pragma unroll
                for (int rr = 0; rr < 9; ++rr) sacc += __shfl(w, rr, 16) * mc[rr];
                la = (lj < Ln) ? (mm + __logf(sacc)) : NEG;
            }
            float x = (lj < Ln) ? (la + endT[lj]) : NEG;
            float mm = x;
#pragma unroll
            for (int off = 1; off < 16; off <<= 1) mm = fmaxf(mm, __shfl_xor(mm, off, 16));
            float se = __expf(x - mm);
#pragma unroll
            for (int off = 1; off < 16; off <<= 1) se += __shfl_xor(se, off, 16);
            if (lj == 0) {
                float denom = mm + __logf(se);
                float numer = numq[bb * 4 + 0] + numq[bb * 4 + 1]
                            + numq[bb * 4 + 2] + numq[bb * 4 + 3];
                int   sm    = msq[bb * 4 + 0] + msq[bb * 4 + 1]
                            + msq[bb * 4 + 2] + msq[bb * 4 + 3];
                int   last  = label[bb * Tn + sm - 1];
                nllArr[bb]  = denom - (numer + endT[last]);   // = -llh[b]
            }
        }
    }
    __syncthreads();

    if (tid < 64) {
        float pv = nllArr[tid];
#pragma unroll
        for (int off = 32; off > 0; off >>= 1) pv += __shfl_xor(pv, off);
        if (tid == 0) out[0] = pv * (1.0f / Bn);
    }
}

extern "C" void kernel_launch(void* const* d_in, const int* in_sizes, int n_in,
                              void* d_out, int out_size, void* d_ws, size_t ws_size,
                              hipStream_t stream)
{
    // inputs: 0=length(unused) 1=word2vec 2=mask 3=label 4=W 5=b 6=start 7=end 8=trans
    const float* wv    = (const float*)d_in[1];
    const int*   mask  = (const int*)d_in[2];
    const int*   label = (const int*)d_in[3];
    const float* Wm    = (const float*)d_in[4];
    const float* bias  = (const float*)d_in[5];
    const float* st    = (const float*)d_in[6];
    const float* en    = (const float*)d_in[7];
    const float* tr    = (const float*)d_in[8];

    float* ws      = (float*)d_ws;
    float* Mq      = ws;                   // 256*81 = 20736
    float* lgq     = ws + 20736;           // 256*9  = 2304
    float* numq    = ws + 23040;           // 256
    int*   msq     = (int*)(ws + 23296);   // 256
    float* em0     = ws + 23552;           // 64*9 = 576
    int*   cnt     = (int*)(ws + 24128);   // 1
    float* out     = (float*)d_out;

    // workspace poisoned between iterations: zero the election counter
    hipMemsetAsync(cnt, 0, sizeof(int), stream);

    hipLaunchKernelGGL(emis_q_kernel, dim3(NBLKS), dim3(512), 0, stream,
                       wv, Wm, bias, mask, label, tr, st, en,
                       Mq, lgq, numq, msq, em0, cnt, out);
}

// Round 9
// 41.475 us; speedup vs baseline: 1.1994x; 1.1994x over previous
//
#include <hip/hip_runtime.h>
#include <hip/hip_bf16.h>

// BERT_CRF: R2's champion structure (40.07 us) with DOUBLED wave concurrency.
// B=64, T=512, H=768, L=9.
//
// Clean concurrency experiment: grid stays 256 = (b, quarter) -- 1 block/CU,
// W staged ONCE per CU (R2-identical traffic) -- but 1024 threads/block
// (16 waves/CU, 2x R2). Waves pair as (tile 0..7, k-half): each wave runs
// 12 MFMA k-steps over K=384 with R2's exact per-lane A-load pattern;
// kh=1 dumps acc to an 8KB LDS accbuf, kh=0 adds halves, bias+exp -> ldsE
// (R7-proven K-split mechanics, minus R7's confound of 4x W-staging).
// Everything downstream (numerator, 8 chunk products, 8->4->2->1 combine,
// K2 comb_kernel with election) is R2 VERBATIM (passed, absmax 0).
//
// Hypothesis being tested: demand-read BW scales with wave concurrency
// (m13: 6.3 TB/s @ 32 waves/CU; R2: 2.8 TB/s @ 8 waves/CU). If total >=
// 40 us, refuted -> R2 is the floor.

#define Bn 64
#define Tn 512
#define Hn 768
#define Ln 9
#define EMS 12     // padded LDS emission row stride (floats)
#define CS 16      // time steps per chunk
#define NCHQ 8     // chunks per quarter
#define QT 128     // timesteps per block
#define KSTEPS 24  // 768 / 32
#define KH 12      // k-steps per half

typedef short bf16x8 __attribute__((ext_vector_type(8)));   // 8 bf16 (4 VGPRs)
typedef float f32x4  __attribute__((ext_vector_type(4)));   // 4 fp32 acc

__device__ __forceinline__ short f2bf(float f) {
    return (short)__builtin_bit_cast(unsigned short, __float2bfloat16(f));
}

// ---------------- K1: per-(batch,quarter), 16 waves ----------------
__global__ __launch_bounds__(1024) void emis_q_kernel(
    const float* __restrict__ wv, const float* __restrict__ Wm,
    const float* __restrict__ bias, const int* __restrict__ mask,
    const int* __restrict__ label, const float* __restrict__ trans,
    const float* __restrict__ startT,
    float* __restrict__ Mq, float* __restrict__ lgq,
    float* __restrict__ numq, int* __restrict__ msq,
    float* __restrict__ em0, int* __restrict__ cnt)
{
    __shared__ bf16x8 wlds[KSTEPS * 64];     // 24576 B, W B-fragments
    __shared__ float4 accbuf[8][64];         // 8192 B, k-half partials
    __shared__ float  ldsE[QT][EMS];         // exp(emissions), 6144 B
    __shared__ int    ldsM[QT];              // mask slice
    __shared__ float  eTs[81];               // exp(transitions)
    __shared__ float  sM[NCHQ][Ln][Ln];      // chunk product matrices
    __shared__ float  sLg[NCHQ][Ln];         // chunk row log-scales
    __shared__ float  sp[16];
    __shared__ int    si[16];

    const int tid   = threadIdx.x;
    const int lane  = tid & 63;
    const int wid   = tid >> 6;              // 0..15
    const int tile  = wid >> 1;              // 0..7: rows [tile*16, +16)
    const int kh    = wid & 1;               // k half
    const int bid   = blockIdx.x;
    const int b     = bid >> 2;
    const int q     = bid & 3;
    const int tbase = q * QT;

    if (bid == 0 && tid == 0) cnt[0] = 0;    // K2 runs strictly after K1
    if (tid < 81) eTs[tid] = __expf(trans[tid]);

    // Stage W (L=9 x H=768 fp32) as bf16 B-fragments in MFMA lane order:
    // entry (kk, lane): lane holds B[k = kk*32 + (lane>>4)*8 + j][n = lane&15],
    // B[k][n] = W[n][k]; n >= 9 -> zeros.  (R2 verbatim, stride 1024)
    for (int idx = tid; idx < KSTEPS * 64; idx += 1024) {
        const int kk = idx >> 6, ln = idx & 63;
        const int n = ln & 15, kb2 = ln >> 4;
        bf16x8 v;
        if (n < Ln) {
            const float* src = Wm + n * Hn + kk * 32 + kb2 * 8;
#pragma unroll
            for (int j = 0; j < 8; ++j) v[j] = f2bf(src[j]);
        } else {
#pragma unroll
            for (int j = 0; j < 8; ++j) v[j] = 0;
        }
        wlds[idx] = v;
    }
    if (tid < QT) ldsM[tid] = mask[b * Tn + tbase + tid];
    __syncthreads();

    // ---- emission phase: K-split, wave (tile,kh), 12 MFMA steps ----
    {
        const int m  = lane & 15;            // A row within tile
        const int kb = lane >> 4;            // k-subblock (8 elems)
        const float* abase = wv + (size_t)(bid * QT + tile * 16 + m) * Hn
                           + kh * 384 + kb * 8;

        f32x4 acc = {0.f, 0.f, 0.f, 0.f};
#pragma unroll 4
        for (int kk = 0; kk < KH; ++kk) {
            float4 x0 = *reinterpret_cast<const float4*>(abase + kk * 32);
            float4 x1 = *reinterpret_cast<const float4*>(abase + kk * 32 + 4);
            bf16x8 a;
            a[0] = f2bf(x0.x); a[1] = f2bf(x0.y); a[2] = f2bf(x0.z); a[3] = f2bf(x0.w);
            a[4] = f2bf(x1.x); a[5] = f2bf(x1.y); a[6] = f2bf(x1.z); a[7] = f2bf(x1.w);
            bf16x8 bfr = wlds[(kh * KH + kk) * 64 + lane];
            acc = __builtin_amdgcn_mfma_f32_16x16x32_bf16(a, bfr, acc, 0, 0, 0);
        }

        if (kh == 1) {
            float4 o; o.x = acc[0]; o.y = acc[1]; o.z = acc[2]; o.w = acc[3];
            accbuf[tile][lane] = o;
        }
        __syncthreads();
        if (kh == 0) {
            // C/D layout: col = lane&15, row = (lane>>4)*4 + r (R2-proven).
            float4 o = accbuf[tile][lane];
            float ov[4] = {o.x, o.y, o.z, o.w};
            const int l = lane & 15;
            if (l < Ln) {
                const float bl = bias[l];
#pragma unroll
                for (int r = 0; r < 4; ++r) {
                    const int lrow = tile * 16 + (lane >> 4) * 4 + r;
                    ldsE[lrow][l] = __expf(acc[r] + ov[r] + bl);
                }
            }
        }
    }
    __syncthreads();

    // ---- numerator partials (threads 0..127, one t each; R2 verbatim) ----
    float part = 0.f; int ms = 0;
    if (tid < QT) {
        const int gt  = tbase + tid;
        const int tag = label[b * Tn + gt];
        const int mk  = ldsM[tid];
        ms = mk;
        if (gt == 0) {
            part = startT[tag] + __logf(ldsE[0][tag]);
        } else if (mk) {
            const int prev = label[b * Tn + gt - 1];
            part = trans[prev * Ln + tag] + __logf(ldsE[tid][tag]);
        }
    }
#pragma unroll
    for (int off = 32; off > 0; off >>= 1) {
        part += __shfl_xor(part, off);
        ms   += __shfl_xor(ms, off);
    }
    if (lane == 0) { sp[wid] = part; si[wid] = ms; }
    __syncthreads();

    // ---- chunk products (threads 0..71; R2 verbatim) ----
    if (tid < NCHQ * Ln) {
        float Tr[81];
#pragma unroll
        for (int i = 0; i < 81; ++i) Tr[i] = eTs[i];
        const int r = tid % Ln;
        const int c = tid / Ln;

        float v[9];
#pragma unroll
        for (int k = 0; k < 9; ++k) v[k] = (k == r) ? 1.f : 0.f;
        float lg = 0.f;

        int t0 = tbase + c * CS; if (t0 == 0) t0 = 1;   // only (q==0,c==0)
        const int t1 = tbase + (c + 1) * CS;

        int lt = t0 - tbase;
        float4 e0v = *reinterpret_cast<const float4*>(&ldsE[lt][0]);
        float4 e1v = *reinterpret_cast<const float4*>(&ldsE[lt][4]);
        float  e8  = ldsE[lt][8];
        int    mk  = ldsM[lt];

        for (int t = t0; t < t1; ++t) {
            float4 p0 = make_float4(0.f, 0.f, 0.f, 0.f), p1 = p0;
            float  p8 = 0.f; int pm = 0;
            if (t + 1 < t1) {
                const int nlt = t + 1 - tbase;
                p0 = *reinterpret_cast<const float4*>(&ldsE[nlt][0]);
                p1 = *reinterpret_cast<const float4*>(&ldsE[nlt][4]);
                p8 = ldsE[nlt][8];
                pm = ldsM[nlt];
            }
            if (mk) {
                float e[9] = {e0v.x, e0v.y, e0v.z, e0v.w, e1v.x, e1v.y, e1v.z, e1v.w, e8};
                float nv[9];
#pragma unroll
                for (int jj = 0; jj < 9; ++jj) {
                    float acc = v[0] * Tr[jj];
#pragma unroll
                    for (int k = 1; k < 9; ++k) acc += v[k] * Tr[k * 9 + jj];
                    nv[jj] = acc * e[jj];
                }
                float mx = nv[0];
#pragma unroll
                for (int jj = 1; jj < 9; ++jj) mx = fmaxf(mx, nv[jj]);
                float inv = 1.f / mx;
#pragma unroll
                for (int jj = 0; jj < 9; ++jj) v[jj] = nv[jj] * inv;
                lg += __logf(mx);
            }
            e0v = p0; e1v = p1; e8 = p8; mk = pm;
        }
#pragma unroll
        for (int jj = 0; jj < 9; ++jj) sM[c][r][jj] = v[jj];
        sLg[c][r] = lg;
    }
    // parallel small outputs
    if (q == 0 && tid >= 72 && tid < 81) em0[b * Ln + (tid - 72)] = ldsE[0][tid - 72];
    if (tid == 100) {
        float s = 0.f; int m2 = 0;
#pragma unroll
        for (int i = 0; i < 16; ++i) { s += sp[i]; m2 += si[i]; }
        numq[bid] = s; msq[bid] = m2;
    }
    __syncthreads();

    // ---- pair-combine 8 -> 4 -> 2 (in place; R2 verbatim) ----
    for (int n = 4; n >= 2; n >>= 1) {
        float vout[9]; float lgout = 0.f;
        const bool act = tid < n * Ln;
        int p = 0, r = 0;
        if (act) {
            p = tid / Ln; r = tid % Ln;
            float mB = sLg[2 * p + 1][0];
#pragma unroll
            for (int k = 1; k < 9; ++k) mB = fmaxf(mB, sLg[2 * p + 1][k]);
            float tA[9];
#pragma unroll
            for (int k = 0; k < 9; ++k) tA[k] = sM[2 * p][r][k] * __expf(sLg[2 * p + 1][k] - mB);
#pragma unroll
            for (int jj = 0; jj < 9; ++jj) {
                float acc = tA[0] * sM[2 * p + 1][0][jj];
#pragma unroll
                for (int k = 1; k < 9; ++k) acc += tA[k] * sM[2 * p + 1][k][jj];
                vout[jj] = acc;
            }
            float mx = vout[0];
#pragma unroll
            for (int jj = 1; jj < 9; ++jj) mx = fmaxf(mx, vout[jj]);
            float inv = 1.f / mx;
#pragma unroll
            for (int jj = 0; jj < 9; ++jj) vout[jj] *= inv;
            lgout = sLg[2 * p][r] + mB + __logf(mx);
        }
        __syncthreads();
        if (act) {
#pragma unroll
            for (int jj = 0; jj < 9; ++jj) sM[p][r][jj] = vout[jj];
            sLg[p][r] = lgout;
        }
        __syncthreads();
    }

    // ---- final pair -> global quarter matrix (R2 verbatim) ----
    if (tid < Ln) {
        const int r = tid;
        float mB = sLg[1][0];
#pragma unroll
        for (int k = 1; k < 9; ++k) mB = fmaxf(mB, sLg[1][k]);
        float tA[9];
#pragma unroll
        for (int k = 0; k < 9; ++k) tA[k] = sM[0][r][k] * __expf(sLg[1][k] - mB);
        float v[9];
#pragma unroll
        for (int jj = 0; jj < 9; ++jj) {
            float acc = tA[0] * sM[1][0][jj];
#pragma unroll
            for (int k = 1; k < 9; ++k) acc += tA[k] * sM[1][k][jj];
            v[jj] = acc;
        }
        float mx = v[0];
#pragma unroll
        for (int jj = 1; jj < 9; ++jj) mx = fmaxf(mx, v[jj]);
        float inv = 1.f / mx;
#pragma unroll
        for (int jj = 0; jj < 9; ++jj) Mq[bid * 81 + r * 9 + jj] = v[jj] * inv;
        lgq[bid * Ln + r] = sLg[0][r] + mB + __logf(mx);
    }
}

// ---------------- K2: combine 4 quarter matrices per batch (R2 verbatim) ----------------
__global__ __launch_bounds__(64) void comb_kernel(
    const float* __restrict__ Mq, const float* __restrict__ lgq,
    const float* __restrict__ numq, const int* __restrict__ msq,
    const float* __restrict__ em0, const int* __restrict__ label,
    const float* __restrict__ startT, const float* __restrict__ endT,
    float* __restrict__ partial, int* __restrict__ cnt, float* __restrict__ out)
{
    __shared__ float cM[4][Ln][Ln];
    __shared__ float cLg[4][Ln];
    __shared__ float cem[Ln];
    __shared__ float cnum[4];
    __shared__ int   cms[4];

    const int b = blockIdx.x, tid = threadIdx.x;

    for (int i = tid; i < 4 * 81; i += 64) cM[i / 81][(i % 81) / 9][i % 9] = Mq[b * 324 + i];
    for (int i = tid; i < 4 * 9; i += 64)  cLg[i / 9][i % 9] = lgq[b * 36 + i];
    if (tid < Ln) cem[tid] = em0[b * Ln + tid];
    if (tid < 4) { cnum[tid] = numq[b * 4 + tid]; cms[tid] = msq[b * 4 + tid]; }
    __syncthreads();

    if (tid < 16) {
        const int lj = tid;
        const float NEG = -1e30f;
        float la = (lj < Ln) ? (startT[lj] + __logf(cem[lj])) : NEG;
        for (int c = 0; c < 4; ++c) {
            float mc[9];
#pragma unroll
            for (int rr = 0; rr < 9; ++rr) mc[rr] = (lj < Ln) ? cM[c][rr][lj] : 0.f;
            float x = (lj < Ln) ? (la + cLg[c][lj]) : NEG;
            float mm = x;
#pragma unroll
            for (int off = 1; off < 16; off <<= 1) mm = fmaxf(mm, __shfl_xor(mm, off, 16));
            float w = __expf(x - mm);                 // lj>=9 -> 0
            float sacc = 0.f;
#pragma unroll
            for (int rr = 0; rr < 9; ++rr) sacc += __shfl(w, rr, 16) * mc[rr];
            la = (lj < Ln) ? (mm + __logf(sacc)) : NEG;
        }
        float x = (lj < Ln) ? (la + endT[lj]) : NEG;
        float mm = x;
#pragma unroll
        for (int off = 1; off < 16; off <<= 1) mm = fmaxf(mm, __shfl_xor(mm, off, 16));
        float se = __expf(x - mm);
#pragma unroll
        for (int off = 1; off < 16; off <<= 1) se += __shfl_xor(se, off, 16);
        if (lj == 0) {
            float denom = mm + __logf(se);
            float numer = cnum[0] + cnum[1] + cnum[2] + cnum[3];
            int   sm    = cms[0] + cms[1] + cms[2] + cms[3];
            int   last  = label[b * Tn + sm - 1];
            partial[b]  = denom - (numer + endT[last]);   // = -llh[b]
        }
    }

    // last block reduces partials -> out (proven election pattern)
    int old = 0;
    if (tid == 0) {
        __threadfence();
        old = atomicAdd(cnt, 1);
    }
    old = __shfl(old, 0);
    if (old == Bn - 1) {
        __threadfence();                 // acquire: other blocks' partial[] visible
        float pv = partial[tid];
#pragma unroll
        for (int off = 32; off > 0; off >>= 1) pv += __shfl_xor(pv, off);
        if (tid == 0) out[0] = pv * (1.0f / Bn);
    }
}

extern "C" void kernel_launch(void* const* d_in, const int* in_sizes, int n_in,
                              void* d_out, int out_size, void* d_ws, size_t ws_size,
                              hipStream_t stream)
{
    // inputs: 0=length(unused) 1=word2vec 2=mask 3=label 4=W 5=b 6=start 7=end 8=trans
    const float* wv    = (const float*)d_in[1];
    const int*   mask  = (const int*)d_in[2];
    const int*   label = (const int*)d_in[3];
    const float* Wm    = (const float*)d_in[4];
    const float* bias  = (const float*)d_in[5];
    const float* st    = (const float*)d_in[6];
    const float* en    = (const float*)d_in[7];
    const float* tr    = (const float*)d_in[8];

    float* ws      = (float*)d_ws;
    float* Mq      = ws;                   // 256*81 = 20736
    float* lgq     = ws + 20736;           // 256*9  = 2304
    float* numq    = ws + 23040;           // 256
    int*   msq     = (int*)(ws + 23296);   // 256
    float* em0     = ws + 23552;           // 64*9 = 576
    float* partial = ws + 24128;           // 64
    int*   cnt     = (int*)(ws + 24192);   // 1
    float* out     = (float*)d_out;

    hipLaunchKernelGGL(emis_q_kernel, dim3(256), dim3(1024), 0, stream,
                       wv, Wm, bias, mask, label, tr, st,
                       Mq, lgq, numq, msq, em0, cnt);
    hipLaunchKernelGGL(comb_kernel, dim3(Bn), dim3(64), 0, stream,
                       Mq, lgq, numq, msq, em0, label, st, en,
                       partial, cnt, out);
}